// Round 2
// baseline (1729.079 us; speedup 1.0000x reference)
//
#include <hip/hip_runtime.h>
#include <hip/hip_bf16.h>
#include <cmath>

#define BN_EPS 1e-5f
#define SLOPE 0.2f

__device__ __forceinline__ float lrelu(float x) { return x >= 0.f ? x : SLOPE * x; }
__device__ __forceinline__ float bfl(unsigned u) { return __uint_as_float(u << 16); }
__device__ __forceinline__ float bfh(unsigned u) { return __uint_as_float(u & 0xffff0000u); }
__device__ __forceinline__ unsigned short f2bf(float f) {
    __hip_bfloat16 h = __float2bfloat16(f);
    return *reinterpret_cast<unsigned short*>(&h);
}

// ----------------- CSR build (group edges by dst) -----------------
__global__ void k_count(const int* __restrict__ ei, int E, int n, int* __restrict__ cnt) {
    int g = blockIdx.x * blockDim.x + threadIdx.x;
    int tot = E + n;
    if (g >= tot) return;
    int dst = (g < E) ? ei[E + g] : (g - E);   // self-loop tail
    atomicAdd(&cnt[dst], 1);
}

__global__ void k_scan1(const int* __restrict__ cnt, int* __restrict__ out,
                        int* __restrict__ bsums, int n) {
    __shared__ int tmp[256];
    int t = threadIdx.x;
    int g = blockIdx.x * 256 + t;
    tmp[t] = (g < n) ? cnt[g] : 0;
    __syncthreads();
    for (int off = 1; off < 256; off <<= 1) {
        int a = (t >= off) ? tmp[t - off] : 0;
        __syncthreads();
        tmp[t] += a;
        __syncthreads();
    }
    if (g < n) out[g] = tmp[t];
    if (t == 255) bsums[blockIdx.x] = tmp[255];
}

__global__ void k_scan2(int* __restrict__ bsums, int nb) {  // nb <= 512
    __shared__ int tmp[512];
    int t = threadIdx.x;
    tmp[t] = (t < nb) ? bsums[t] : 0;
    __syncthreads();
    for (int off = 1; off < 512; off <<= 1) {
        int a = (t >= off) ? tmp[t - off] : 0;
        __syncthreads();
        tmp[t] += a;
        __syncthreads();
    }
    if (t < nb) bsums[t] = (t == 0) ? 0 : tmp[t - 1];
}

__global__ void k_scan3(int* __restrict__ row_ptr, const int* __restrict__ bsums, int n) {
    int g = blockIdx.x * blockDim.x + threadIdx.x;
    if (g == 0) row_ptr[0] = 0;
    if (g < n) row_ptr[g + 1] += bsums[g >> 8];
}

__global__ void k_scatter(const int* __restrict__ ei, int E, int n,
                          const int* __restrict__ row_ptr, int* __restrict__ cur,
                          int* __restrict__ csr) {
    int g = blockIdx.x * blockDim.x + threadIdx.x;
    int tot = E + n;
    if (g >= tot) return;
    int src, dst;
    if (g < E) { src = ei[g]; dst = ei[E + g]; }
    else       { src = g - E; dst = src; }
    int pos = atomicAdd(&cur[dst], 1);
    csr[row_ptr[dst] + pos] = src;
}

// ----------------- fused GEMM: h = X@W (+optional BN+ReLU on X), bf16 h out,
//                   s = h@a_s, d = h@a_d in epilogue -----------------
// 64 rows x CD cols per block; 256 threads; thread (tr=t>>4, tc=t&15) owns
// 4 rows x {hf*64 + tc*4 .. +3} cols (NH=CD/64 half-tiles).
template <int CD, bool BN_IN>
__global__ __launch_bounds__(256) void k_gemm_f(
    const float* __restrict__ X, const float* __restrict__ W,
    const float* __restrict__ bnsums, const float* __restrict__ gg,
    const float* __restrict__ bb, const float* __restrict__ a_s,
    const float* __restrict__ a_d, unsigned short* __restrict__ hb,
    float* __restrict__ s_out, float* __restrict__ d_out, int n) {
    constexpr int NH = CD / 64;           // 2 (CD=128) or 1 (CD=64)
    __shared__ float al[64 * 132];        // A tile [row][k], pad 132 (bank-audited)
    __shared__ float wl[32 * CD];         // W K-chunk
    __shared__ float sc[128];
    __shared__ float sh[128];
    int t = threadIdx.x;
    int r0 = blockIdx.x * 64;
    if constexpr (BN_IN) {
        if (t < 128) {
            float invn = 1.f / (float)n;
            float mu = bnsums[t] * invn;
            float var = bnsums[128 + t] * invn - mu * mu;
            float scv = gg[t] * rsqrtf(var + BN_EPS);
            sc[t] = scv;
            sh[t] = bb[t] - mu * scv;
        }
        __syncthreads();
    }
    // stage A tile (apply BN+ReLU if fused)
    for (int i = t * 4; i < 64 * 128; i += 1024) {
        int rr = i >> 7, cc = i & 127;
        float4 v = make_float4(0.f, 0.f, 0.f, 0.f);
        if (r0 + rr < n) v = *(const float4*)&X[(size_t)(r0 + rr) * 128 + cc];
        if constexpr (BN_IN) {
            v.x = fmaxf(0.f, v.x * sc[cc + 0] + sh[cc + 0]);
            v.y = fmaxf(0.f, v.y * sc[cc + 1] + sh[cc + 1]);
            v.z = fmaxf(0.f, v.z * sc[cc + 2] + sh[cc + 2]);
            v.w = fmaxf(0.f, v.w * sc[cc + 3] + sh[cc + 3]);
        }
        *(float4*)&al[rr * 132 + cc] = v;
    }
    int tr = t >> 4, tc = t & 15;
    float acc[4][NH][4] = {};
    for (int kc = 0; kc < 128; kc += 32) {
        __syncthreads();   // A ready (1st iter) / wl readers done (later iters)
        for (int i = t * 4; i < 32 * CD; i += 1024)
            *(float4*)&wl[i] = *(const float4*)&W[(size_t)kc * CD + i];
        __syncthreads();
        for (int k = 0; k < 32; ++k) {
            float av[4];
#pragma unroll
            for (int r = 0; r < 4; ++r) av[r] = al[(tr * 4 + r) * 132 + kc + k];
#pragma unroll
            for (int hf = 0; hf < NH; ++hf) {
                float4 wv = *(const float4*)&wl[k * CD + hf * 64 + tc * 4];
#pragma unroll
                for (int r = 0; r < 4; ++r) {
                    acc[r][hf][0] += av[r] * wv.x;
                    acc[r][hf][1] += av[r] * wv.y;
                    acc[r][hf][2] += av[r] * wv.z;
                    acc[r][hf][3] += av[r] * wv.w;
                }
            }
        }
    }
    // epilogue: bf16 h write + per-thread score partials
    float ps[4], pd[4];
#pragma unroll
    for (int r = 0; r < 4; ++r) {
        ps[r] = 0.f; pd[r] = 0.f;
#pragma unroll
        for (int hf = 0; hf < NH; ++hf) {
            int cb = hf * 64 + tc * 4;
#pragma unroll
            for (int j = 0; j < 4; ++j) {
                ps[r] += acc[r][hf][j] * a_s[cb + j];
                pd[r] += acc[r][hf][j] * a_d[cb + j];
            }
        }
        int row = r0 + tr * 4 + r;
        if (row < n) {
#pragma unroll
            for (int hf = 0; hf < NH; ++hf) {
                int cb = hf * 64 + tc * 4;
                unsigned u0 = (unsigned)f2bf(acc[r][hf][0]) | ((unsigned)f2bf(acc[r][hf][1]) << 16);
                unsigned u1 = (unsigned)f2bf(acc[r][hf][2]) | ((unsigned)f2bf(acc[r][hf][3]) << 16);
                *(uint2*)&hb[(size_t)row * CD + cb] = make_uint2(u0, u1);
            }
        }
    }
    // reduce score partials across the 16 col-threads of each row (reuse al)
    __syncthreads();
    float* reds = al;
    float* redd = al + 64 * 16;
#pragma unroll
    for (int r = 0; r < 4; ++r) {
        reds[(tr * 4 + r) * 16 + tc] = ps[r];
        redd[(tr * 4 + r) * 16 + tc] = pd[r];
    }
    __syncthreads();
    if (t < 64) {
        int row = r0 + t;
        if (row < n) {
            float ssum = 0.f, dsum = 0.f;
#pragma unroll
            for (int i = 0; i < 16; ++i) { ssum += reds[t * 16 + i]; dsum += redd[t * 16 + i]; }
            s_out[row] = ssum;
            d_out[row] = dsum;
        }
    }
}

// ----------------- GAT aggregate: one wave per dst, bf16 gather -----------------
// pass1: segment-max of lrelu logits (lane-strided), cache logits linearly.
// pass2: half-waves take alternating edges, unrolled x2 (4 chains in flight).
template <int DIM>
__global__ __launch_bounds__(256) void k_aggregate(
    const unsigned short* __restrict__ hb, const float* __restrict__ s,
    const float* __restrict__ d, const int* __restrict__ rowp,
    const int* __restrict__ csr, float* __restrict__ logits,
    float* __restrict__ out, int n) {
    int wave = (blockIdx.x * blockDim.x + threadIdx.x) >> 6;
    int lane = threadIdx.x & 63;
    if (wave >= n) return;
    int beg = rowp[wave], end = rowp[wave + 1];
    float dv = d[wave];
    float m = -INFINITY;
    for (int e = beg + lane; e < end; e += 64) {
        float l = lrelu(s[csr[e]] + dv);
        logits[e] = l;
        m = fmaxf(m, l);
    }
    for (int off = 32; off; off >>= 1) m = fmaxf(m, __shfl_xor(m, off));
    constexpr int FPL = DIM / 32;                 // feats per lane (4 or 2)
    int half = lane >> 5, lh = lane & 31;
    float acc[FPL] = {};
    float denom = 0.f;
    for (int e = beg + half; e < end; e += 4) {
        int e1 = e + 2;
        bool v1 = e1 < end;
        int i0 = csr[e];
        int i1 = v1 ? csr[e1] : i0;
        float w0 = __expf(logits[e] - m);
        float w1 = v1 ? __expf(logits[e1] - m) : 0.f;
        if constexpr (FPL == 4) {
            uint2 p0 = *(const uint2*)&hb[(size_t)i0 * DIM + lh * 4];
            uint2 p1 = *(const uint2*)&hb[(size_t)i1 * DIM + lh * 4];
            acc[0] += w0 * bfl(p0.x) + w1 * bfl(p1.x);
            acc[1] += w0 * bfh(p0.x) + w1 * bfh(p1.x);
            acc[2] += w0 * bfl(p0.y) + w1 * bfl(p1.y);
            acc[3] += w0 * bfh(p0.y) + w1 * bfh(p1.y);
        } else {
            unsigned p0 = *(const unsigned*)&hb[(size_t)i0 * DIM + lh * 2];
            unsigned p1 = *(const unsigned*)&hb[(size_t)i1 * DIM + lh * 2];
            acc[0] += w0 * bfl(p0) + w1 * bfl(p1);
            acc[1] += w0 * bfh(p0) + w1 * bfh(p1);
        }
        denom += w0 + w1;
    }
    denom += __shfl_xor(denom, 32);
#pragma unroll
    for (int f = 0; f < FPL; ++f) acc[f] += __shfl_xor(acc[f], 32);
    if (half == 0) {
        float inv = 1.f / denom;
        float* orow = out + (size_t)wave * DIM;
#pragma unroll
        for (int f = 0; f < FPL; ++f) orow[lh * FPL + f] = acc[f] * inv;
    }
}

// ----------------- BatchNorm -----------------
template <int CD>
__global__ void k_bn_stats(const float* __restrict__ x, float* __restrict__ sums, int n) {
    constexpr int RPB = 256 / CD;
    int t = threadIdx.x;
    int c = t & (CD - 1);
    int rl = t / CD;
    float s = 0.f, sq = 0.f;
    for (int r = blockIdx.x * RPB + rl; r < n; r += gridDim.x * RPB) {
        float v = x[(size_t)r * CD + c];
        s += v;
        sq += v * v;
    }
    __shared__ float ls[256], lq[256];
    ls[t] = s; lq[t] = sq;
    __syncthreads();
    if (t < CD) {
#pragma unroll
        for (int j = 1; j < RPB; ++j) { s += ls[t + j * CD]; sq += lq[t + j * CD]; }
        atomicAdd(&sums[c], s);
        atomicAdd(&sums[CD + c], sq);
    }
}

template <int CD>
__global__ void k_bn_apply(const float* __restrict__ x, const float* __restrict__ sums,
                           const float* __restrict__ g, const float* __restrict__ b,
                           float* __restrict__ out, int n) {
    size_t i = (size_t)blockIdx.x * blockDim.x + threadIdx.x;
    size_t tot = (size_t)n * CD;
    if (i >= tot) return;
    int c = (int)(i & (CD - 1));
    float invn = 1.f / (float)n;
    float mu = sums[c] * invn;
    float var = sums[CD + c] * invn - mu * mu;
    float v = (x[i] - mu) * rsqrtf(var + BN_EPS) * g[c] + b[c];
    out[i] = fmaxf(v, 0.f);
}

// ----------------- launch -----------------
extern "C" void kernel_launch(void* const* d_in, const int* in_sizes, int n_in,
                              void* d_out, int out_size, void* d_ws, size_t ws_size,
                              hipStream_t stream) {
    const float* x   = (const float*)d_in[0];
    const int*   ei  = (const int*)  d_in[1];
    const float* W0  = (const float*)d_in[2];
    const float* as0 = (const float*)d_in[3];
    const float* ad0 = (const float*)d_in[4];
    const float* g0  = (const float*)d_in[5];
    const float* b0  = (const float*)d_in[6];
    const float* W1  = (const float*)d_in[7];
    const float* as1 = (const float*)d_in[8];
    const float* ad1 = (const float*)d_in[9];
    const float* g1  = (const float*)d_in[10];
    const float* b1  = (const float*)d_in[11];
    float* out = (float*)d_out;

    const int N_ = in_sizes[0] / 128;  // 100000
    const int E_ = in_sizes[1] / 2;    // 1600000
    const int TOT = E_ + N_;

    // ---- workspace layout (agg1 aliases agg0; hb1 aliases hb0) ----
    char* p = (char*)d_ws;
    float* agg0 = (float*)p;                 p += (size_t)N_ * 128 * 4;
    unsigned short* hb = (unsigned short*)p; p += (size_t)N_ * 128 * 2;
    float* s0   = (float*)p;                 p += (size_t)N_ * 4;
    float* d0   = (float*)p;                 p += (size_t)N_ * 4;
    float* bns0 = (float*)p;                 p += 256 * 4;
    float* bns1 = (float*)p;                 p += 128 * 4;
    int* cnt    = (int*)p;                   p += (size_t)N_ * 4;
    int* cur    = (int*)p;                   p += (size_t)N_ * 4;
    int* rowp   = (int*)p;                   p += (size_t)(N_ + 1) * 4;
    int* bsums  = (int*)p;                   p += 512 * 4;
    int* csr    = (int*)p;                   p += (size_t)TOT * 4;
    float* logits = (float*)p;               p += (size_t)TOT * 4;

    const int nbScan = (N_ + 255) / 256;     // 391 (<=512)

    hipMemsetAsync(cnt, 0, (size_t)N_ * 2 * 4, stream);   // cnt + cur
    hipMemsetAsync(bns0, 0, 384 * 4, stream);             // bns0 + bns1

    // CSR build
    k_count<<<(TOT + 255) / 256, 256, 0, stream>>>(ei, E_, N_, cnt);
    k_scan1<<<nbScan, 256, 0, stream>>>(cnt, rowp + 1, bsums, N_);
    k_scan2<<<1, 512, 0, stream>>>(bsums, nbScan);
    k_scan3<<<nbScan, 256, 0, stream>>>(rowp, bsums, N_);
    k_scatter<<<(TOT + 255) / 256, 256, 0, stream>>>(ei, E_, N_, rowp, cur, csr);

    const int gemmBlocks = (N_ + 63) / 64;
    const int waveBlocks = (N_ + 3) / 4;

    // ---- layer 0 ----
    k_gemm_f<128, false><<<gemmBlocks, 256, 0, stream>>>(
        x, W0, nullptr, nullptr, nullptr, as0, ad0, hb, s0, d0, N_);
    k_aggregate<128><<<waveBlocks, 256, 0, stream>>>(hb, s0, d0, rowp, csr, logits, agg0, N_);
    k_bn_stats<128><<<256, 256, 0, stream>>>(agg0, bns0, N_);

    // ---- layer 1 (BN+ReLU fused into GEMM input staging) ----
    k_gemm_f<64, true><<<gemmBlocks, 256, 0, stream>>>(
        agg0, W1, bns0, g0, b0, as1, ad1, hb, s0, d0, N_);
    k_aggregate<64><<<waveBlocks, 256, 0, stream>>>(hb, s0, d0, rowp, csr, logits, agg0, N_);
    k_bn_stats<64><<<256, 256, 0, stream>>>(agg0, bns1, N_);
    k_bn_apply<64><<<(int)(((size_t)N_ * 64 + 255) / 256), 256, 0, stream>>>(
        agg0, bns1, g1, b1, out, N_);
}

// Round 3
// 591.690 us; speedup vs baseline: 2.9223x; 2.9223x over previous
//
#include <hip/hip_runtime.h>
#include <hip/hip_bf16.h>
#include <cmath>

#define BN_EPS 1e-5f
#define SLOPE 0.2f

typedef __attribute__((ext_vector_type(8))) short bf16x8;
typedef __attribute__((ext_vector_type(4))) float f32x4;

__device__ __forceinline__ float lrelu(float x) { return x >= 0.f ? x : SLOPE * x; }
__device__ __forceinline__ float bfl(unsigned u) { return __uint_as_float(u << 16); }
__device__ __forceinline__ float bfh(unsigned u) { return __uint_as_float(u & 0xffff0000u); }
__device__ __forceinline__ unsigned short f2bf(float f) {
    __hip_bfloat16 h = __float2bfloat16(f);
    return *reinterpret_cast<unsigned short*>(&h);
}

// ----------------- CSR build (group edges by dst) -----------------
__global__ void k_count(const int* __restrict__ ei, int E, int n, int* __restrict__ cnt) {
    int g = blockIdx.x * blockDim.x + threadIdx.x;
    int tot = E + n;
    if (g >= tot) return;
    int dst = (g < E) ? ei[E + g] : (g - E);
    atomicAdd(&cnt[dst], 1);
}

__global__ void k_scan1(const int* __restrict__ cnt, int* __restrict__ out,
                        int* __restrict__ bsums, int n) {
    __shared__ int tmp[256];
    int t = threadIdx.x;
    int g = blockIdx.x * 256 + t;
    tmp[t] = (g < n) ? cnt[g] : 0;
    __syncthreads();
    for (int off = 1; off < 256; off <<= 1) {
        int a = (t >= off) ? tmp[t - off] : 0;
        __syncthreads();
        tmp[t] += a;
        __syncthreads();
    }
    if (g < n) out[g] = tmp[t];
    if (t == 255) bsums[blockIdx.x] = tmp[255];
}

__global__ void k_scan2(int* __restrict__ bsums, int nb) {  // nb <= 512
    __shared__ int tmp[512];
    int t = threadIdx.x;
    tmp[t] = (t < nb) ? bsums[t] : 0;
    __syncthreads();
    for (int off = 1; off < 512; off <<= 1) {
        int a = (t >= off) ? tmp[t - off] : 0;
        __syncthreads();
        tmp[t] += a;
        __syncthreads();
    }
    if (t < nb) bsums[t] = (t == 0) ? 0 : tmp[t - 1];
}

__global__ void k_scan3(int* __restrict__ row_ptr, const int* __restrict__ bsums, int n) {
    int g = blockIdx.x * blockDim.x + threadIdx.x;
    if (g == 0) row_ptr[0] = 0;
    if (g < n) row_ptr[g + 1] += bsums[g >> 8];
}

__global__ void k_scatter(const int* __restrict__ ei, int E, int n,
                          const int* __restrict__ row_ptr, int* __restrict__ cur,
                          int* __restrict__ csr) {
    int g = blockIdx.x * blockDim.x + threadIdx.x;
    int tot = E + n;
    if (g >= tot) return;
    int src, dst;
    if (g < E) { src = ei[g]; dst = ei[E + g]; }
    else       { src = g - E; dst = src; }
    int pos = atomicAdd(&cur[dst], 1);
    csr[row_ptr[dst] + pos] = src;
}

// ----------------- pack W[K=128][CD] fp32 -> bf16 B-fragment order -----------
// chunk = (nt*4 + ks)*64 + (g*16 + n), element j, where k = ks*32 + g*8 + j,
// col = nt*16 + n. A lane l = g*16+n then reads its 16B frag at chunk base + l.
template <int CD>
__global__ void k_packw(const float* __restrict__ W, unsigned short* __restrict__ Wp) {
    int idx = blockIdx.x * 256 + threadIdx.x;
    if (idx >= 128 * CD) return;
    int k = idx / CD, nG = idx % CD;
    int nt = nG >> 4, n = nG & 15, ks = k >> 5, g = (k >> 3) & 3, j = k & 7;
    Wp[(((nt * 4 + ks) * 64) + g * 16 + n) * 8 + j] = f2bf(W[idx]);
}

// ----------------- MFMA GEMM: h = act(X)@W, bf16 h out, s/d scores fused ----
// 256 thr = 4 waves, 64 rows/block, K=128. A-frags direct from global fp32.
template <int CD, bool BN_IN>
__global__ __launch_bounds__(256) void k_gemm_mfma(
    const float* __restrict__ X, const unsigned short* __restrict__ Wp,
    const float* __restrict__ bnsums, const float* __restrict__ gg,
    const float* __restrict__ bb, const float* __restrict__ a_s,
    const float* __restrict__ a_d, unsigned short* __restrict__ hb,
    float* __restrict__ s_out, float* __restrict__ d_out, int n) {
    constexpr int NT = CD / 16;
    __shared__ unsigned short wl[128 * CD];   // packed W frags; reused as out-tile
    __shared__ float sc[128], sh[128];
    int t = threadIdx.x;
    for (int i = t * 8; i < 128 * CD; i += 2048)
        *(uint4*)&wl[i] = *(const uint4*)&Wp[i];
    if constexpr (BN_IN) {
        if (t < 128) {
            float invn = 1.f / (float)n;
            float mu = bnsums[t] * invn;
            float var = bnsums[128 + t] * invn - mu * mu;
            float s = gg[t] * rsqrtf(var + BN_EPS);
            sc[t] = s;
            sh[t] = bb[t] - mu * s;
        }
    }
    __syncthreads();
    int w = t >> 6, l = t & 63;
    int m = l & 15, g = l >> 4;
    int r0 = blockIdx.x * 64;
    int row = r0 + w * 16 + m;
    bool rv = row < n;
    // A fragments (lane holds A[m][ks*32 + g*8 + j])
    bf16x8 af[4];
#pragma unroll
    for (int ks = 0; ks < 4; ++ks) {
        int c0 = ks * 32 + g * 8;
        float4 x0 = make_float4(0.f, 0.f, 0.f, 0.f), x1 = x0;
        if (rv) {
            x0 = *(const float4*)&X[(size_t)row * 128 + c0];
            x1 = *(const float4*)&X[(size_t)row * 128 + c0 + 4];
        }
        float xv[8] = {x0.x, x0.y, x0.z, x0.w, x1.x, x1.y, x1.z, x1.w};
        bf16x8 a;
#pragma unroll
        for (int j = 0; j < 8; ++j) {
            float v = xv[j];
            if constexpr (BN_IN) v = fmaxf(0.f, v * sc[c0 + j] + sh[c0 + j]);
            a[j] = (short)f2bf(v);
        }
        af[ks] = a;
    }
    f32x4 acc[NT];
#pragma unroll
    for (int i = 0; i < NT; ++i) acc[i] = (f32x4){0.f, 0.f, 0.f, 0.f};
#pragma unroll
    for (int ks = 0; ks < 4; ++ks) {
#pragma unroll
        for (int nt = 0; nt < NT; ++nt) {
            bf16x8 b = *(bf16x8*)&wl[(((nt * 4 + ks) * 64) + l) * 8];
            acc[nt] = __builtin_amdgcn_mfma_f32_16x16x32_bf16(af[ks], b, acc[nt], 0, 0, 0);
        }
    }
    // scores from acc: lane holds D[g*4+r][m]; butterfly over the 16 cols
    float ps[4] = {0.f, 0.f, 0.f, 0.f}, pd[4] = {0.f, 0.f, 0.f, 0.f};
#pragma unroll
    for (int nt = 0; nt < NT; ++nt) {
        float as = a_s[nt * 16 + m], ad = a_d[nt * 16 + m];
#pragma unroll
        for (int r = 0; r < 4; ++r) {
            ps[r] += acc[nt][r] * as;
            pd[r] += acc[nt][r] * ad;
        }
    }
#pragma unroll
    for (int off = 1; off < 16; off <<= 1) {
#pragma unroll
        for (int r = 0; r < 4; ++r) {
            ps[r] += __shfl_xor(ps[r], off);
            pd[r] += __shfl_xor(pd[r], off);
        }
    }
    __syncthreads();                    // all waves done reading wl
    unsigned short* ot = wl;            // reuse as 64 x CD bf16 out-tile
#pragma unroll
    for (int nt = 0; nt < NT; ++nt) {
#pragma unroll
        for (int r = 0; r < 4; ++r)
            ot[(w * 16 + g * 4 + r) * CD + nt * 16 + m] = f2bf(acc[nt][r]);
    }
    if (m == 0) {
        int orow = r0 + w * 16 + g * 4;
#pragma unroll
        for (int r = 0; r < 4; ++r) {
            if (orow + r < n) { s_out[orow + r] = ps[r]; d_out[orow + r] = pd[r]; }
        }
    }
    __syncthreads();
    // coalesced bf16 h write (16B chunks)
    constexpr int CPR = CD / 8;         // chunks per row
    for (int c = t; c < 64 * CPR; c += 256) {
        int rr = c / CPR, cc = c % CPR;
        if (r0 + rr < n)
            *(uint4*)&hb[(size_t)(r0 + rr) * CD + cc * 8] = *(uint4*)&ot[rr * CD + cc * 8];
    }
}

// ----------------- GAT aggregate: one wave per dst, bf16 gather -----------------
template <int DIM>
__global__ __launch_bounds__(256) void k_aggregate(
    const unsigned short* __restrict__ hb, const float* __restrict__ s,
    const float* __restrict__ d, const int* __restrict__ rowp,
    const int* __restrict__ csr, float* __restrict__ logits,
    float* __restrict__ out, int n) {
    int wave = (blockIdx.x * blockDim.x + threadIdx.x) >> 6;
    int lane = threadIdx.x & 63;
    if (wave >= n) return;
    int beg = rowp[wave], end = rowp[wave + 1];
    float dv = d[wave];
    float m = -INFINITY;
    for (int e = beg + lane; e < end; e += 64) {
        float l = lrelu(s[csr[e]] + dv);
        logits[e] = l;
        m = fmaxf(m, l);
    }
    for (int off = 32; off; off >>= 1) m = fmaxf(m, __shfl_xor(m, off));
    constexpr int FPL = DIM / 32;
    int half = lane >> 5, lh = lane & 31;
    float acc[FPL] = {};
    float denom = 0.f;
    for (int e = beg + half; e < end; e += 4) {
        int e1 = e + 2;
        bool v1 = e1 < end;
        int i0 = csr[e];
        int i1 = v1 ? csr[e1] : i0;
        float w0 = __expf(logits[e] - m);
        float w1 = v1 ? __expf(logits[e1] - m) : 0.f;
        if constexpr (FPL == 4) {
            uint2 p0 = *(const uint2*)&hb[(size_t)i0 * DIM + lh * 4];
            uint2 p1 = *(const uint2*)&hb[(size_t)i1 * DIM + lh * 4];
            acc[0] += w0 * bfl(p0.x) + w1 * bfl(p1.x);
            acc[1] += w0 * bfh(p0.x) + w1 * bfh(p1.x);
            acc[2] += w0 * bfl(p0.y) + w1 * bfl(p1.y);
            acc[3] += w0 * bfh(p0.y) + w1 * bfh(p1.y);
        } else {
            unsigned p0 = *(const unsigned*)&hb[(size_t)i0 * DIM + lh * 2];
            unsigned p1 = *(const unsigned*)&hb[(size_t)i1 * DIM + lh * 2];
            acc[0] += w0 * bfl(p0) + w1 * bfl(p1);
            acc[1] += w0 * bfh(p0) + w1 * bfh(p1);
        }
        denom += w0 + w1;
    }
    denom += __shfl_xor(denom, 32);
#pragma unroll
    for (int f = 0; f < FPL; ++f) acc[f] += __shfl_xor(acc[f], 32);
    if (half == 0) {
        float inv = 1.f / denom;
        float* orow = out + (size_t)wave * DIM;
#pragma unroll
        for (int f = 0; f < FPL; ++f) orow[lh * FPL + f] = acc[f] * inv;
    }
}

// ----------------- BatchNorm -----------------
template <int CD>
__global__ void k_bn_stats(const float* __restrict__ x, float* __restrict__ sums, int n) {
    constexpr int RPB = 256 / CD;
    int t = threadIdx.x;
    int c = t & (CD - 1);
    int rl = t / CD;
    float s = 0.f, sq = 0.f;
    for (int r = blockIdx.x * RPB + rl; r < n; r += gridDim.x * RPB) {
        float v = x[(size_t)r * CD + c];
        s += v;
        sq += v * v;
    }
    __shared__ float ls[256], lq[256];
    ls[t] = s; lq[t] = sq;
    __syncthreads();
    if (t < CD) {
#pragma unroll
        for (int j = 1; j < RPB; ++j) { s += ls[t + j * CD]; sq += lq[t + j * CD]; }
        atomicAdd(&sums[c], s);
        atomicAdd(&sums[CD + c], sq);
    }
}

template <int CD>
__global__ void k_bn_apply(const float* __restrict__ x, const float* __restrict__ sums,
                           const float* __restrict__ g, const float* __restrict__ b,
                           float* __restrict__ out, int n) {
    size_t i = (size_t)blockIdx.x * blockDim.x + threadIdx.x;
    size_t tot = (size_t)n * CD;
    if (i >= tot) return;
    int c = (int)(i & (CD - 1));
    float invn = 1.f / (float)n;
    float mu = sums[c] * invn;
    float var = sums[CD + c] * invn - mu * mu;
    float v = (x[i] - mu) * rsqrtf(var + BN_EPS) * g[c] + b[c];
    out[i] = fmaxf(v, 0.f);
}

// ----------------- launch -----------------
extern "C" void kernel_launch(void* const* d_in, const int* in_sizes, int n_in,
                              void* d_out, int out_size, void* d_ws, size_t ws_size,
                              hipStream_t stream) {
    const float* x   = (const float*)d_in[0];
    const int*   ei  = (const int*)  d_in[1];
    const float* W0  = (const float*)d_in[2];
    const float* as0 = (const float*)d_in[3];
    const float* ad0 = (const float*)d_in[4];
    const float* g0  = (const float*)d_in[5];
    const float* b0  = (const float*)d_in[6];
    const float* W1  = (const float*)d_in[7];
    const float* as1 = (const float*)d_in[8];
    const float* ad1 = (const float*)d_in[9];
    const float* g1  = (const float*)d_in[10];
    const float* b1  = (const float*)d_in[11];
    float* out = (float*)d_out;

    const int N_ = in_sizes[0] / 128;  // 100000
    const int E_ = in_sizes[1] / 2;    // 1600000
    const int TOT = E_ + N_;

    // ---- workspace layout ----
    char* p = (char*)d_ws;
    float* agg0 = (float*)p;                 p += (size_t)N_ * 128 * 4;
    unsigned short* hb = (unsigned short*)p; p += (size_t)N_ * 128 * 2;
    float* s0   = (float*)p;                 p += (size_t)N_ * 4;
    float* d0   = (float*)p;                 p += (size_t)N_ * 4;
    float* bns0 = (float*)p;                 p += 256 * 4;
    float* bns1 = (float*)p;                 p += 128 * 4;
    int* cnt    = (int*)p;                   p += (size_t)N_ * 4;
    int* cur    = (int*)p;                   p += (size_t)N_ * 4;
    int* rowp   = (int*)p;                   p += (size_t)(N_ + 1) * 4;
    int* bsums  = (int*)p;                   p += 512 * 4;
    int* csr    = (int*)p;                   p += (size_t)TOT * 4;
    float* logits = (float*)p;               p += (size_t)TOT * 4;
    unsigned short* Wp0 = (unsigned short*)p; p += 128 * 128 * 2;
    unsigned short* Wp1 = (unsigned short*)p; p += 128 * 64 * 2;

    const int nbScan = (N_ + 255) / 256;     // 391 (<=512)

    hipMemsetAsync(cnt, 0, (size_t)N_ * 2 * 4, stream);   // cnt + cur
    hipMemsetAsync(bns0, 0, 384 * 4, stream);             // bns0 + bns1

    // CSR build
    k_count<<<(TOT + 255) / 256, 256, 0, stream>>>(ei, E_, N_, cnt);
    k_scan1<<<nbScan, 256, 0, stream>>>(cnt, rowp + 1, bsums, N_);
    k_scan2<<<1, 512, 0, stream>>>(bsums, nbScan);
    k_scan3<<<nbScan, 256, 0, stream>>>(rowp, bsums, N_);
    k_scatter<<<(TOT + 255) / 256, 256, 0, stream>>>(ei, E_, N_, rowp, cur, csr);

    // W packing
    k_packw<128><<<64, 256, 0, stream>>>(W0, Wp0);
    k_packw<64><<<32, 256, 0, stream>>>(W1, Wp1);

    const int gemmBlocks = (N_ + 63) / 64;
    const int waveBlocks = (N_ + 3) / 4;

    // ---- layer 0 ----
    k_gemm_mfma<128, false><<<gemmBlocks, 256, 0, stream>>>(
        x, Wp0, nullptr, nullptr, nullptr, as0, ad0, hb, s0, d0, N_);
    k_aggregate<128><<<waveBlocks, 256, 0, stream>>>(hb, s0, d0, rowp, csr, logits, agg0, N_);
    k_bn_stats<128><<<256, 256, 0, stream>>>(agg0, bns0, N_);

    // ---- layer 1 (BN+ReLU fused into GEMM A-load) ----
    k_gemm_mfma<64, true><<<gemmBlocks, 256, 0, stream>>>(
        agg0, Wp1, bns0, g0, b0, as1, ad1, hb, s0, d0, N_);
    k_aggregate<64><<<waveBlocks, 256, 0, stream>>>(hb, s0, d0, rowp, csr, logits, agg0, N_);
    k_bn_stats<64><<<256, 256, 0, stream>>>(agg0, bns1, N_);
    k_bn_apply<64><<<(int)(((size_t)N_ * 64 + 255) / 256), 256, 0, stream>>>(
        agg0, bns1, g1, b1, out, N_);
}

// Round 4
// 476.281 us; speedup vs baseline: 3.6304x; 1.2423x over previous
//
#include <hip/hip_runtime.h>
#include <hip/hip_bf16.h>
#include <cmath>

#define BN_EPS 1e-5f
#define SLOPE 0.2f

typedef __attribute__((ext_vector_type(8))) short bf16x8;
typedef __attribute__((ext_vector_type(4))) float f32x4;

__device__ __forceinline__ float lrelu(float x) { return x >= 0.f ? x : SLOPE * x; }
__device__ __forceinline__ float bfl(unsigned u) { return __uint_as_float(u << 16); }
__device__ __forceinline__ float bfh(unsigned u) { return __uint_as_float(u & 0xffff0000u); }
__device__ __forceinline__ unsigned short f2bf(float f) {
    __hip_bfloat16 h = __float2bfloat16(f);
    return *reinterpret_cast<unsigned short*>(&h);
}

// ======== CSR build via two-level bucket sort (bucket = 256 dst nodes) ========
// Phase 1: global bucket histogram (LDS-aggregated).
__global__ __launch_bounds__(512) void k_hist(const int* __restrict__ ei, int E, int n,
                                              int nbk, int* __restrict__ gcnt) {
    __shared__ int h[512];
    int t = threadIdx.x;
    for (int i = t; i < nbk; i += 512) h[i] = 0;
    __syncthreads();
    int base = blockIdx.x * 8192;
    int tot = E + n;
#pragma unroll
    for (int k = 0; k < 16; ++k) {
        int i = base + k * 512 + t;
        if (i < tot) {
            int dst = (i < E) ? ei[E + i] : (i - E);
            atomicAdd(&h[dst >> 8], 1);
        }
    }
    __syncthreads();
    for (int i = t; i < nbk; i += 512)
        if (h[i]) atomicAdd(&gcnt[i], h[i]);
}

// Phase 2: scan bucket counts -> bases (nbk <= 512, one block).
__global__ __launch_bounds__(512) void k_bscan(const int* __restrict__ gcnt,
                                               int* __restrict__ gbase,
                                               int* __restrict__ gnext, int nbk) {
    __shared__ int tmp[512];
    int t = threadIdx.x;
    int v = (t < nbk) ? gcnt[t] : 0;
    tmp[t] = v;
    __syncthreads();
    for (int off = 1; off < 512; off <<= 1) {
        int a = (t >= off) ? tmp[t - off] : 0;
        __syncthreads();
        tmp[t] += a;
        __syncthreads();
    }
    int ex = tmp[t] - v;   // exclusive
    if (t < nbk) { gbase[t] = ex; gnext[t] = ex; }
    if (t == nbk - 1) gbase[nbk] = tmp[t];
}

// Phase 3: rank-scatter (src,dst) pairs into bucket-contiguous bbuf.
__global__ __launch_bounds__(512) void k_bucket(const int* __restrict__ ei, int E, int n,
                                                int nbk, int* __restrict__ gnext,
                                                int2* __restrict__ bbuf) {
    __shared__ int h[512], off[512], c2[512];
    int t = threadIdx.x;
    for (int i = t; i < nbk; i += 512) { h[i] = 0; c2[i] = 0; }
    __syncthreads();
    int base = blockIdx.x * 8192;
    int tot = E + n;
    int srcv[16], dstv[16];
#pragma unroll
    for (int k = 0; k < 16; ++k) {
        int i = base + k * 512 + t;
        dstv[k] = -1;
        if (i < tot) {
            int s, d;
            if (i < E) { s = ei[i]; d = ei[E + i]; }
            else       { s = i - E; d = s; }
            srcv[k] = s; dstv[k] = d;
            atomicAdd(&h[d >> 8], 1);
        }
    }
    __syncthreads();
    for (int i = t; i < nbk; i += 512)
        if (h[i]) off[i] = atomicAdd(&gnext[i], h[i]);
    __syncthreads();
#pragma unroll
    for (int k = 0; k < 16; ++k) {
        int d = dstv[k];
        if (d >= 0) {
            int b = d >> 8;
            int r = atomicAdd(&c2[b], 1);
            bbuf[off[b] + r] = make_int2(srcv[k], d);
        }
    }
}

// Phase 4: per-bucket LDS counting sort -> row_ptr + csr. One block per bucket.
__global__ __launch_bounds__(256) void k_csr(const int2* __restrict__ bbuf,
                                             const int* __restrict__ gbase,
                                             int* __restrict__ rowp, int* __restrict__ csr,
                                             int n, int nbk) {
    __shared__ int cnt[256], scn[256];
    int b = blockIdx.x;
    int t = threadIdx.x;
    int beg = gbase[b], end = gbase[b + 1];
    int node0 = b << 8;
    cnt[t] = 0;
    __syncthreads();
    for (int i = beg + t; i < end; i += 256)
        atomicAdd(&cnt[bbuf[i].y & 255], 1);
    __syncthreads();
    int v = cnt[t];
    scn[t] = v;
    __syncthreads();
    for (int off = 1; off < 256; off <<= 1) {
        int a = (t >= off) ? scn[t - off] : 0;
        __syncthreads();
        scn[t] += a;
        __syncthreads();
    }
    int ex = scn[t] - v;
    if (node0 + t < n) rowp[node0 + t] = beg + ex;
    if (b == nbk - 1 && t == 0) rowp[n] = end;
    // reuse cnt as cursor
    cnt[t] = 0;
    __syncthreads();
    for (int i = beg + t; i < end; i += 256) {
        int2 e = bbuf[i];
        int ld = e.y & 255;
        int pos = atomicAdd(&cnt[ld], 1);
        csr[beg + (scn[ld] - ((ld == t) ? v : (scn[ld] - (scn[ld] - 0)))) + 0] = 0; // placeholder (never compiled)
    }
}

// NOTE: the placeholder line above is wrong — real implementation below.

// ======== pack W[K=128][CD] fp32 -> bf16 B-fragment order ========
template <int CD>
__global__ void k_packw(const float* __restrict__ W, unsigned short* __restrict__ Wp) {
    int idx = blockIdx.x * 256 + threadIdx.x;
    if (idx >= 128 * CD) return;
    int k = idx / CD, nG = idx % CD;
    int nt = nG >> 4, nn = nG & 15, ks = k >> 5, g = (k >> 3) & 3, j = k & 7;
    Wp[(((nt * 4 + ks) * 64) + g * 16 + nn) * 8 + j] = f2bf(W[idx]);
}

// ======== MFMA GEMM: h = act(X)@W, bf16 h out, s/d scores fused ========
template <int CD, bool BN_IN>
__global__ __launch_bounds__(256) void k_gemm_mfma(
    const float* __restrict__ X, const unsigned short* __restrict__ Wp,
    const float* __restrict__ bnsums, const float* __restrict__ gg,
    const float* __restrict__ bb, const float* __restrict__ a_s,
    const float* __restrict__ a_d, unsigned short* __restrict__ hb,
    float* __restrict__ s_out, float* __restrict__ d_out, int n) {
    constexpr int NT = CD / 16;
    __shared__ unsigned short wl[128 * CD];
    __shared__ float sc[128], sh[128];
    int t = threadIdx.x;
    for (int i = t * 8; i < 128 * CD; i += 2048)
        *(uint4*)&wl[i] = *(const uint4*)&Wp[i];
    if constexpr (BN_IN) {
        if (t < 128) {
            float invn = 1.f / (float)n;
            float mu = bnsums[t] * invn;
            float var = bnsums[128 + t] * invn - mu * mu;
            float s = gg[t] * rsqrtf(var + BN_EPS);
            sc[t] = s;
            sh[t] = bb[t] - mu * s;
        }
    }
    __syncthreads();
    int w = t >> 6, l = t & 63;
    int m = l & 15, g = l >> 4;
    int r0 = blockIdx.x * 64;
    int row = r0 + w * 16 + m;
    bool rv = row < n;
    bf16x8 af[4];
#pragma unroll
    for (int ks = 0; ks < 4; ++ks) {
        int c0 = ks * 32 + g * 8;
        float4 x0 = make_float4(0.f, 0.f, 0.f, 0.f), x1 = x0;
        if (rv) {
            x0 = *(const float4*)&X[(size_t)row * 128 + c0];
            x1 = *(const float4*)&X[(size_t)row * 128 + c0 + 4];
        }
        float xv[8] = {x0.x, x0.y, x0.z, x0.w, x1.x, x1.y, x1.z, x1.w};
        bf16x8 a;
#pragma unroll
        for (int j = 0; j < 8; ++j) {
            float v = xv[j];
            if constexpr (BN_IN) v = fmaxf(0.f, v * sc[c0 + j] + sh[c0 + j]);
            a[j] = (short)f2bf(v);
        }
        af[ks] = a;
    }
    f32x4 acc[NT];
#pragma unroll
    for (int i = 0; i < NT; ++i) acc[i] = (f32x4){0.f, 0.f, 0.f, 0.f};
#pragma unroll
    for (int ks = 0; ks < 4; ++ks) {
#pragma unroll
        for (int nt = 0; nt < NT; ++nt) {
            bf16x8 bfr = *(bf16x8*)&wl[(((nt * 4 + ks) * 64) + l) * 8];
            acc[nt] = __builtin_amdgcn_mfma_f32_16x16x32_bf16(af[ks], bfr, acc[nt], 0, 0, 0);
        }
    }
    float ps[4] = {0.f, 0.f, 0.f, 0.f}, pd[4] = {0.f, 0.f, 0.f, 0.f};
#pragma unroll
    for (int nt = 0; nt < NT; ++nt) {
        float as = a_s[nt * 16 + m], ad = a_d[nt * 16 + m];
#pragma unroll
        for (int r = 0; r < 4; ++r) {
            ps[r] += acc[nt][r] * as;
            pd[r] += acc[nt][r] * ad;
        }
    }
#pragma unroll
    for (int off = 1; off < 16; off <<= 1) {
#pragma unroll
        for (int r = 0; r < 4; ++r) {
            ps[r] += __shfl_xor(ps[r], off);
            pd[r] += __shfl_xor(pd[r], off);
        }
    }
    __syncthreads();
    unsigned short* ot = wl;
#pragma unroll
    for (int nt = 0; nt < NT; ++nt) {
#pragma unroll
        for (int r = 0; r < 4; ++r)
            ot[(w * 16 + g * 4 + r) * CD + nt * 16 + m] = f2bf(acc[nt][r]);
    }
    if (m == 0) {
        int orow = r0 + w * 16 + g * 4;
#pragma unroll
        for (int r = 0; r < 4; ++r) {
            if (orow + r < n) { s_out[orow + r] = ps[r]; d_out[orow + r] = pd[r]; }
        }
    }
    __syncthreads();
    constexpr int CPR = CD / 8;
    for (int c = t; c < 64 * CPR; c += 256) {
        int rr = c / CPR, cc = c % CPR;
        if (r0 + rr < n)
            *(uint4*)&hb[(size_t)(r0 + rr) * CD + cc * 8] = *(uint4*)&ot[rr * CD + cc * 8];
    }
}

// ======== GAT aggregate: one wave per dst, bf16 gather ========
template <int DIM>
__global__ __launch_bounds__(256) void k_aggregate(
    const unsigned short* __restrict__ hb, const float* __restrict__ s,
    const float* __restrict__ d, const int* __restrict__ rowp,
    const int* __restrict__ csr, float* __restrict__ logits,
    float* __restrict__ out, int n) {
    int wave = (blockIdx.x * blockDim.x + threadIdx.x) >> 6;
    int lane = threadIdx.x & 63;
    if (wave >= n) return;
    int beg = rowp[wave], end = rowp[wave + 1];
    float dv = d[wave];
    float m = -INFINITY;
    for (int e = beg + lane; e < end; e += 64) {
        float l = lrelu(s[csr[e]] + dv);
        logits[e] = l;
        m = fmaxf(m, l);
    }
    for (int off = 32; off; off >>= 1) m = fmaxf(m, __shfl_xor(m, off));
    constexpr int FPL = DIM / 32;
    int half = lane >> 5, lh = lane & 31;
    float acc[FPL] = {};
    float denom = 0.f;
    for (int e = beg + half; e < end; e += 4) {
        int e1 = e + 2;
        bool v1 = e1 < end;
        int i0 = csr[e];
        int i1 = v1 ? csr[e1] : i0;
        float w0 = __expf(logits[e] - m);
        float w1 = v1 ? __expf(logits[e1] - m) : 0.f;
        if constexpr (FPL == 4) {
            uint2 p0 = *(const uint2*)&hb[(size_t)i0 * DIM + lh * 4];
            uint2 p1 = *(const uint2*)&hb[(size_t)i1 * DIM + lh * 4];
            acc[0] += w0 * bfl(p0.x) + w1 * bfl(p1.x);
            acc[1] += w0 * bfh(p0.x) + w1 * bfh(p1.x);
            acc[2] += w0 * bfl(p0.y) + w1 * bfl(p1.y);
            acc[3] += w0 * bfh(p0.y) + w1 * bfh(p1.y);
        } else {
            unsigned p0 = *(const unsigned*)&hb[(size_t)i0 * DIM + lh * 2];
            unsigned p1 = *(const unsigned*)&hb[(size_t)i1 * DIM + lh * 2];
            acc[0] += w0 * bfl(p0) + w1 * bfl(p1);
            acc[1] += w0 * bfh(p0) + w1 * bfh(p1);
        }
        denom += w0 + w1;
    }
    denom += __shfl_xor(denom, 32);
#pragma unroll
    for (int f = 0; f < FPL; ++f) acc[f] += __shfl_xor(acc[f], 32);
    if (half == 0) {
        float inv = 1.f / denom;
        float* orow = out + (size_t)wave * DIM;
#pragma unroll
        for (int f = 0; f < FPL; ++f) orow[lh * FPL + f] = acc[f] * inv;
    }
}

// ======== BatchNorm ========
template <int CD>
__global__ void k_bn_stats(const float* __restrict__ x, float* __restrict__ sums, int n) {
    constexpr int RPB = 256 / CD;
    int t = threadIdx.x;
    int c = t & (CD - 1);
    int rl = t / CD;
    float s = 0.f, sq = 0.f;
    for (int r = blockIdx.x * RPB + rl; r < n; r += gridDim.x * RPB) {
        float v = x[(size_t)r * CD + c];
        s += v;
        sq += v * v;
    }
    __shared__ float ls[256], lq[256];
    ls[t] = s; lq[t] = sq;
    __syncthreads();
    if (t < CD) {
#pragma unroll
        for (int j = 1; j < RPB; ++j) { s += ls[t + j * CD]; sq += lq[t + j * CD]; }
        atomicAdd(&sums[c], s);
        atomicAdd(&sums[CD + c], sq);
    }
}

template <int CD>
__global__ void k_bn_apply(const float* __restrict__ x, const float* __restrict__ sums,
                           const float* __restrict__ g, const float* __restrict__ b,
                           float* __restrict__ out, int n) {
    size_t i = (size_t)blockIdx.x * blockDim.x + threadIdx.x;
    size_t tot = (size_t)n * CD;
    if (i >= tot) return;
    int c = (int)(i & (CD - 1));
    float invn = 1.f / (float)n;
    float mu = sums[c] * invn;
    float var = sums[CD + c] * invn - mu * mu;
    float v = (x[i] - mu) * rsqrtf(var + BN_EPS) * g[c] + b[c];
    out[i] = fmaxf(v, 0.f);
}

// ======== real k_csr (replaces placeholder above) ========
__global__ __launch_bounds__(256) void k_csr2(const int2* __restrict__ bbuf,
                                              const int* __restrict__ gbase,
                                              int* __restrict__ rowp, int* __restrict__ csr,
                                              int n, int nbk) {
    __shared__ int cnt[256], scn[256];
    int b = blockIdx.x;
    int t = threadIdx.x;
    int beg = gbase[b], end = gbase[b + 1];
    int node0 = b << 8;
    cnt[t] = 0;
    __syncthreads();
    for (int i = beg + t; i < end; i += 256)
        atomicAdd(&cnt[bbuf[i].y & 255], 1);
    __syncthreads();
    int v = cnt[t];
    scn[t] = v;
    __syncthreads();
    for (int off = 1; off < 256; off <<= 1) {
        int a = (t >= off) ? scn[t - off] : 0;
        __syncthreads();
        scn[t] += a;
        __syncthreads();
    }
    int ex = scn[t] - v;          // exclusive scan = row offset within bucket
    if (node0 + t < n) rowp[node0 + t] = beg + ex;
    if (b == nbk - 1 && t == 0) rowp[n] = end;
    cnt[t] = ex;                  // cursor starts at exclusive offset
    __syncthreads();
    for (int i = beg + t; i < end; i += 256) {
        int2 e = bbuf[i];
        int pos = atomicAdd(&cnt[e.y & 255], 1);
        csr[beg + pos] = e.x;
    }
}

// ======== launch ========
extern "C" void kernel_launch(void* const* d_in, const int* in_sizes, int n_in,
                              void* d_out, int out_size, void* d_ws, size_t ws_size,
                              hipStream_t stream) {
    const float* x   = (const float*)d_in[0];
    const int*   ei  = (const int*)  d_in[1];
    const float* W0  = (const float*)d_in[2];
    const float* as0 = (const float*)d_in[3];
    const float* ad0 = (const float*)d_in[4];
    const float* g0  = (const float*)d_in[5];
    const float* b0  = (const float*)d_in[6];
    const float* W1  = (const float*)d_in[7];
    const float* as1 = (const float*)d_in[8];
    const float* ad1 = (const float*)d_in[9];
    const float* g1  = (const float*)d_in[10];
    const float* b1  = (const float*)d_in[11];
    float* out = (float*)d_out;

    const int N_ = in_sizes[0] / 128;  // 100000
    const int E_ = in_sizes[1] / 2;    // 1600000
    const int TOT = E_ + N_;
    const int nbk = (N_ + 255) >> 8;   // 391 buckets

    // ---- workspace layout (8B-aligned blocks first) ----
    char* p = (char*)d_ws;
    float* agg0 = (float*)p;                 p += (size_t)N_ * 128 * 4;
    unsigned short* hb = (unsigned short*)p; p += (size_t)N_ * 128 * 2;
    int2* bbuf  = (int2*)p;                  p += (size_t)TOT * 8;
    float* s0   = (float*)p;                 p += (size_t)N_ * 4;
    float* d0   = (float*)p;                 p += (size_t)N_ * 4;
    float* bns0 = (float*)p;                 p += 256 * 4;
    float* bns1 = (float*)p;                 p += 128 * 4;
    int* gcnt   = (int*)p;                   p += 512 * 4;
    int* gbase  = (int*)p;                   p += 513 * 4;
    int* gnext  = (int*)p;                   p += 512 * 4;
    int* rowp   = (int*)p;                   p += (size_t)(N_ + 1) * 4;
    int* csr    = (int*)p;                   p += (size_t)TOT * 4;
    float* logits = (float*)p;               p += (size_t)TOT * 4;
    unsigned short* Wp0 = (unsigned short*)p; p += 128 * 128 * 2;
    unsigned short* Wp1 = (unsigned short*)p; p += 128 * 64 * 2;

    hipMemsetAsync(gcnt, 0, 512 * 4, stream);
    hipMemsetAsync(bns0, 0, 384 * 4, stream);             // bns0 + bns1

    // CSR build (bucketed)
    const int ebBlocks = (TOT + 8191) / 8192;
    k_hist<<<ebBlocks, 512, 0, stream>>>(ei, E_, N_, nbk, gcnt);
    k_bscan<<<1, 512, 0, stream>>>(gcnt, gbase, gnext, nbk);
    k_bucket<<<ebBlocks, 512, 0, stream>>>(ei, E_, N_, nbk, gnext, bbuf);
    k_csr2<<<nbk, 256, 0, stream>>>(bbuf, gbase, rowp, csr, N_, nbk);

    // W packing
    k_packw<128><<<64, 256, 0, stream>>>(W0, Wp0);
    k_packw<64><<<32, 256, 0, stream>>>(W1, Wp1);

    const int gemmBlocks = (N_ + 63) / 64;
    const int waveBlocks = (N_ + 3) / 4;

    // ---- layer 0 ----
    k_gemm_mfma<128, false><<<gemmBlocks, 256, 0, stream>>>(
        x, Wp0, nullptr, nullptr, nullptr, as0, ad0, hb, s0, d0, N_);
    k_aggregate<128><<<waveBlocks, 256, 0, stream>>>(hb, s0, d0, rowp, csr, logits, agg0, N_);
    k_bn_stats<128><<<256, 256, 0, stream>>>(agg0, bns0, N_);

    // ---- layer 1 (BN+ReLU fused into GEMM A-load) ----
    k_gemm_mfma<64, true><<<gemmBlocks, 256, 0, stream>>>(
        agg0, Wp1, bns0, g0, b0, as1, ad1, hb, s0, d0, N_);
    k_aggregate<64><<<waveBlocks, 256, 0, stream>>>(hb, s0, d0, rowp, csr, logits, agg0, N_);
    k_bn_stats<64><<<256, 256, 0, stream>>>(agg0, bns1, N_);
    k_bn_apply<64><<<(int)(((size_t)N_ * 64 + 255) / 256), 256, 0, stream>>>(
        agg0, bns1, g1, b1, out, N_);
}

// Round 5
// 398.707 us; speedup vs baseline: 4.3367x; 1.1946x over previous
//
#include <hip/hip_runtime.h>
#include <hip/hip_bf16.h>
#include <cmath>

#define BN_EPS 1e-5f
#define SLOPE 0.2f

typedef __attribute__((ext_vector_type(8))) short bf16x8;
typedef __attribute__((ext_vector_type(4))) float f32x4;

__device__ __forceinline__ float lrelu(float x) { return x >= 0.f ? x : SLOPE * x; }
__device__ __forceinline__ float bfl(unsigned u) { return __uint_as_float(u << 16); }
__device__ __forceinline__ float bfh(unsigned u) { return __uint_as_float(u & 0xffff0000u); }
__device__ __forceinline__ float bf2f(unsigned short u) { return __uint_as_float((unsigned)u << 16); }
__device__ __forceinline__ unsigned short f2bf(float f) {
    __hip_bfloat16 h = __float2bfloat16(f);
    return *reinterpret_cast<unsigned short*>(&h);
}

// ======== CSR build via two-level bucket sort (bucket = 256 dst nodes) ========
__global__ __launch_bounds__(512) void k_hist(const int* __restrict__ ei, int E, int n,
                                              int nbk, int* __restrict__ gcnt) {
    __shared__ int h[512];
    int t = threadIdx.x;
    for (int i = t; i < nbk; i += 512) h[i] = 0;
    __syncthreads();
    int base = blockIdx.x * 8192;
    int tot = E + n;
#pragma unroll
    for (int k = 0; k < 16; ++k) {
        int i = base + k * 512 + t;
        if (i < tot) {
            int dst = (i < E) ? ei[E + i] : (i - E);
            atomicAdd(&h[dst >> 8], 1);
        }
    }
    __syncthreads();
    for (int i = t; i < nbk; i += 512)
        if (h[i]) atomicAdd(&gcnt[i], h[i]);
}

__global__ __launch_bounds__(512) void k_bscan(const int* __restrict__ gcnt,
                                               int* __restrict__ gbase,
                                               int* __restrict__ gnext, int nbk) {
    __shared__ int tmp[512];
    int t = threadIdx.x;
    int v = (t < nbk) ? gcnt[t] : 0;
    tmp[t] = v;
    __syncthreads();
    for (int off = 1; off < 512; off <<= 1) {
        int a = (t >= off) ? tmp[t - off] : 0;
        __syncthreads();
        tmp[t] += a;
        __syncthreads();
    }
    int ex = tmp[t] - v;
    if (t < nbk) { gbase[t] = ex; gnext[t] = ex; }
    if (t == nbk - 1) gbase[nbk] = tmp[t];
}

__global__ __launch_bounds__(512) void k_bucket(const int* __restrict__ ei, int E, int n,
                                                int nbk, int* __restrict__ gnext,
                                                int2* __restrict__ bbuf) {
    __shared__ int h[512], off[512], c2[512];
    int t = threadIdx.x;
    for (int i = t; i < nbk; i += 512) { h[i] = 0; c2[i] = 0; }
    __syncthreads();
    int base = blockIdx.x * 8192;
    int tot = E + n;
    int srcv[16], dstv[16];
#pragma unroll
    for (int k = 0; k < 16; ++k) {
        int i = base + k * 512 + t;
        dstv[k] = -1;
        if (i < tot) {
            int s, d;
            if (i < E) { s = ei[i]; d = ei[E + i]; }
            else       { s = i - E; d = s; }
            srcv[k] = s; dstv[k] = d;
            atomicAdd(&h[d >> 8], 1);
        }
    }
    __syncthreads();
    for (int i = t; i < nbk; i += 512)
        if (h[i]) off[i] = atomicAdd(&gnext[i], h[i]);
    __syncthreads();
#pragma unroll
    for (int k = 0; k < 16; ++k) {
        int d = dstv[k];
        if (d >= 0) {
            int b = d >> 8;
            int r = atomicAdd(&c2[b], 1);
            bbuf[off[b] + r] = make_int2(srcv[k], d);
        }
    }
}

__global__ __launch_bounds__(256) void k_csr2(const int2* __restrict__ bbuf,
                                              const int* __restrict__ gbase,
                                              int* __restrict__ rowp, int* __restrict__ csr,
                                              int n, int nbk) {
    __shared__ int cnt[256], scn[256];
    int b = blockIdx.x;
    int t = threadIdx.x;
    int beg = gbase[b], end = gbase[b + 1];
    int node0 = b << 8;
    cnt[t] = 0;
    __syncthreads();
    for (int i = beg + t; i < end; i += 256)
        atomicAdd(&cnt[bbuf[i].y & 255], 1);
    __syncthreads();
    int v = cnt[t];
    scn[t] = v;
    __syncthreads();
    for (int off = 1; off < 256; off <<= 1) {
        int a = (t >= off) ? scn[t - off] : 0;
        __syncthreads();
        scn[t] += a;
        __syncthreads();
    }
    int ex = scn[t] - v;
    if (node0 + t < n) rowp[node0 + t] = beg + ex;
    if (b == nbk - 1 && t == 0) rowp[n] = end;
    cnt[t] = ex;
    __syncthreads();
    for (int i = beg + t; i < end; i += 256) {
        int2 e = bbuf[i];
        int pos = atomicAdd(&cnt[e.y & 255], 1);
        csr[beg + pos] = e.x;
    }
}

// ======== pack W[K=128][CD] fp32 -> bf16 B-fragment order ========
template <int CD>
__global__ void k_packw(const float* __restrict__ W, unsigned short* __restrict__ Wp) {
    int idx = blockIdx.x * 256 + threadIdx.x;
    if (idx >= 128 * CD) return;
    int k = idx / CD, nG = idx % CD;
    int nt = nG >> 4, nn = nG & 15, ks = k >> 5, g = (k >> 3) & 3, j = k & 7;
    Wp[(((nt * 4 + ks) * 64) + g * 16 + nn) * 8 + j] = f2bf(W[idx]);
}

// ======== MFMA GEMM: h = act(X)@W, bf16 h out, s/d scores fused ========
// XBF: X is bf16 (layer-1 aggregate); else fp32.
template <int CD, bool BN_IN, bool XBF>
__global__ __launch_bounds__(256) void k_gemm_mfma(
    const void* __restrict__ Xv, const unsigned short* __restrict__ Wp,
    const float* __restrict__ bnsums, const float* __restrict__ gg,
    const float* __restrict__ bb, const float* __restrict__ a_s,
    const float* __restrict__ a_d, unsigned short* __restrict__ hb,
    float* __restrict__ s_out, float* __restrict__ d_out, int n) {
    constexpr int NT = CD / 16;
    const float* Xf = (const float*)Xv;
    const unsigned short* Xh = (const unsigned short*)Xv;
    __shared__ unsigned short wl[128 * CD];
    __shared__ float sc[128], sh[128];
    int t = threadIdx.x;
    for (int i = t * 8; i < 128 * CD; i += 2048)
        *(uint4*)&wl[i] = *(const uint4*)&Wp[i];
    if constexpr (BN_IN) {
        if (t < 128) {
            float invn = 1.f / (float)n;
            float mu = bnsums[t] * invn;
            float var = bnsums[128 + t] * invn - mu * mu;
            float s = gg[t] * rsqrtf(var + BN_EPS);
            sc[t] = s;
            sh[t] = bb[t] - mu * s;
        }
    }
    __syncthreads();
    int w = t >> 6, l = t & 63;
    int m = l & 15, g = l >> 4;
    int r0 = blockIdx.x * 64;
    int row = r0 + w * 16 + m;
    bool rv = row < n;
    bf16x8 af[4];
#pragma unroll
    for (int ks = 0; ks < 4; ++ks) {
        int c0 = ks * 32 + g * 8;
        float xv[8];
        if constexpr (XBF) {
            uint4 u = make_uint4(0, 0, 0, 0);
            if (rv) u = *(const uint4*)&Xh[(size_t)row * 128 + c0];
            unsigned uu[4] = {u.x, u.y, u.z, u.w};
#pragma unroll
            for (int q = 0; q < 4; ++q) { xv[2 * q] = bfl(uu[q]); xv[2 * q + 1] = bfh(uu[q]); }
        } else {
            float4 x0 = make_float4(0.f, 0.f, 0.f, 0.f), x1 = x0;
            if (rv) {
                x0 = *(const float4*)&Xf[(size_t)row * 128 + c0];
                x1 = *(const float4*)&Xf[(size_t)row * 128 + c0 + 4];
            }
            xv[0] = x0.x; xv[1] = x0.y; xv[2] = x0.z; xv[3] = x0.w;
            xv[4] = x1.x; xv[5] = x1.y; xv[6] = x1.z; xv[7] = x1.w;
        }
        bf16x8 a;
#pragma unroll
        for (int j = 0; j < 8; ++j) {
            float v = xv[j];
            if constexpr (BN_IN) v = fmaxf(0.f, v * sc[c0 + j] + sh[c0 + j]);
            a[j] = (short)f2bf(v);
        }
        af[ks] = a;
    }
    f32x4 acc[NT];
#pragma unroll
    for (int i = 0; i < NT; ++i) acc[i] = (f32x4){0.f, 0.f, 0.f, 0.f};
#pragma unroll
    for (int ks = 0; ks < 4; ++ks) {
#pragma unroll
        for (int nt = 0; nt < NT; ++nt) {
            bf16x8 bfr = *(bf16x8*)&wl[(((nt * 4 + ks) * 64) + l) * 8];
            acc[nt] = __builtin_amdgcn_mfma_f32_16x16x32_bf16(af[ks], bfr, acc[nt], 0, 0, 0);
        }
    }
    float ps[4] = {0.f, 0.f, 0.f, 0.f}, pd[4] = {0.f, 0.f, 0.f, 0.f};
#pragma unroll
    for (int nt = 0; nt < NT; ++nt) {
        float as = a_s[nt * 16 + m], ad = a_d[nt * 16 + m];
#pragma unroll
        for (int r = 0; r < 4; ++r) {
            ps[r] += acc[nt][r] * as;
            pd[r] += acc[nt][r] * ad;
        }
    }
#pragma unroll
    for (int off = 1; off < 16; off <<= 1) {
#pragma unroll
        for (int r = 0; r < 4; ++r) {
            ps[r] += __shfl_xor(ps[r], off);
            pd[r] += __shfl_xor(pd[r], off);
        }
    }
    __syncthreads();
    unsigned short* ot = wl;
#pragma unroll
    for (int nt = 0; nt < NT; ++nt) {
#pragma unroll
        for (int r = 0; r < 4; ++r)
            ot[(w * 16 + g * 4 + r) * CD + nt * 16 + m] = f2bf(acc[nt][r]);
    }
    if (m == 0) {
        int orow = r0 + w * 16 + g * 4;
#pragma unroll
        for (int r = 0; r < 4; ++r) {
            if (orow + r < n) { s_out[orow + r] = ps[r]; d_out[orow + r] = pd[r]; }
        }
    }
    __syncthreads();
    constexpr int CPR = CD / 8;
    for (int c = t; c < 64 * CPR; c += 256) {
        int rr = c / CPR, cc = c % CPR;
        if (r0 + rr < n)
            *(uint4*)&hb[(size_t)(r0 + rr) * CD + cc * 8] = *(uint4*)&ot[rr * CD + cc * 8];
    }
}

// ======== GAT aggregate v2: one wave/dst, no-max softmax, 16B/lane gather ====
// LPE lanes per edge (16B = 8 bf16 feats each); EPW edges per slot; unroll x2.
template <int DIM, bool OUT_BF>
__global__ __launch_bounds__(256) void k_agg(
    const unsigned short* __restrict__ hb, const float* __restrict__ s,
    const float* __restrict__ d, const int* __restrict__ rowp,
    const int* __restrict__ csr, void* __restrict__ outv, int n) {
    constexpr int LPE = DIM / 8;
    constexpr int EPW = 64 / LPE;
    int wid = (blockIdx.x * blockDim.x + threadIdx.x) >> 6;
    int lane = threadIdx.x & 63;
    if (wid >= n) return;
    int beg = rowp[wid], end = rowp[wid + 1];
    float dv = d[wid];
    int grp = lane / LPE, ll = lane % LPE;
    float acc[8] = {};
    float denom = 0.f;
    for (int e = beg + grp; e < end; e += EPW * 2) {
        int eB = e + EPW;
        bool vB = eB < end;
        int iA = csr[e];
        int iB = vB ? csr[eB] : iA;
        float wA = __expf(lrelu(s[iA] + dv));
        float wB = vB ? __expf(lrelu(s[iB] + dv)) : 0.f;
        uint4 pA = *(const uint4*)&hb[(size_t)iA * DIM + ll * 8];
        uint4 pB = *(const uint4*)&hb[(size_t)iB * DIM + ll * 8];
        denom += wA + wB;
        unsigned ua[4] = {pA.x, pA.y, pA.z, pA.w};
        unsigned ub[4] = {pB.x, pB.y, pB.z, pB.w};
#pragma unroll
        for (int q = 0; q < 4; ++q) {
            acc[2 * q]     += wA * bfl(ua[q]) + wB * bfl(ub[q]);
            acc[2 * q + 1] += wA * bfh(ua[q]) + wB * bfh(ub[q]);
        }
    }
#pragma unroll
    for (int off = LPE; off < 64; off <<= 1) {
        denom += __shfl_xor(denom, off);
#pragma unroll
        for (int f = 0; f < 8; ++f) acc[f] += __shfl_xor(acc[f], off);
    }
    if (grp == 0) {
        float inv = 1.f / denom;
        if constexpr (OUT_BF) {
            unsigned u[4];
#pragma unroll
            for (int q = 0; q < 4; ++q)
                u[q] = (unsigned)f2bf(acc[2 * q] * inv) |
                       ((unsigned)f2bf(acc[2 * q + 1] * inv) << 16);
            *(uint4*)((unsigned short*)outv + (size_t)wid * DIM + ll * 8) =
                make_uint4(u[0], u[1], u[2], u[3]);
        } else {
            float* orow = (float*)outv + (size_t)wid * DIM + ll * 8;
            *(float4*)&orow[0] = make_float4(acc[0] * inv, acc[1] * inv, acc[2] * inv, acc[3] * inv);
            *(float4*)&orow[4] = make_float4(acc[4] * inv, acc[5] * inv, acc[6] * inv, acc[7] * inv);
        }
    }
}

// ======== BatchNorm stats (XBF: bf16 input) ========
template <int CD, bool XBF>
__global__ void k_bn_stats(const void* __restrict__ xv, float* __restrict__ sums, int n) {
    const float* xf = (const float*)xv;
    const unsigned short* xh = (const unsigned short*)xv;
    constexpr int RPB = 256 / CD;
    int t = threadIdx.x;
    int c = t & (CD - 1);
    int rl = t / CD;
    float s = 0.f, sq = 0.f;
    for (int r = blockIdx.x * RPB + rl; r < n; r += gridDim.x * RPB) {
        float v = XBF ? bf2f(xh[(size_t)r * CD + c]) : xf[(size_t)r * CD + c];
        s += v;
        sq += v * v;
    }
    __shared__ float ls[256], lq[256];
    ls[t] = s; lq[t] = sq;
    __syncthreads();
    if (t < CD) {
#pragma unroll
        for (int j = 1; j < RPB; ++j) { s += ls[t + j * CD]; sq += lq[t + j * CD]; }
        atomicAdd(&sums[c], s);
        atomicAdd(&sums[CD + c], sq);
    }
}

template <int CD>
__global__ void k_bn_apply(const float* __restrict__ x, const float* __restrict__ sums,
                           const float* __restrict__ g, const float* __restrict__ b,
                           float* __restrict__ out, int n) {
    size_t i = (size_t)blockIdx.x * blockDim.x + threadIdx.x;
    size_t tot = (size_t)n * CD;
    if (i >= tot) return;
    int c = (int)(i & (CD - 1));
    float invn = 1.f / (float)n;
    float mu = sums[c] * invn;
    float var = sums[CD + c] * invn - mu * mu;
    float v = (x[i] - mu) * rsqrtf(var + BN_EPS) * g[c] + b[c];
    out[i] = fmaxf(v, 0.f);
}

// ======== launch ========
extern "C" void kernel_launch(void* const* d_in, const int* in_sizes, int n_in,
                              void* d_out, int out_size, void* d_ws, size_t ws_size,
                              hipStream_t stream) {
    const float* x   = (const float*)d_in[0];
    const int*   ei  = (const int*)  d_in[1];
    const float* W0  = (const float*)d_in[2];
    const float* as0 = (const float*)d_in[3];
    const float* ad0 = (const float*)d_in[4];
    const float* g0  = (const float*)d_in[5];
    const float* b0  = (const float*)d_in[6];
    const float* W1  = (const float*)d_in[7];
    const float* as1 = (const float*)d_in[8];
    const float* ad1 = (const float*)d_in[9];
    const float* g1  = (const float*)d_in[10];
    const float* b1  = (const float*)d_in[11];
    float* out = (float*)d_out;

    const int N_ = in_sizes[0] / 128;  // 100000
    const int E_ = in_sizes[1] / 2;    // 1600000
    const int TOT = E_ + N_;
    const int nbk = (N_ + 255) >> 8;   // 391 buckets

    // ---- workspace layout (all chunks 8B-aligned) ----
    char* p = (char*)d_ws;
    unsigned short* hb   = (unsigned short*)p; p += (size_t)N_ * 128 * 2;
    unsigned short* aggB = (unsigned short*)p; p += (size_t)N_ * 128 * 2;
    float* agg1 = (float*)p;                   p += (size_t)N_ * 64 * 4;
    int2* bbuf  = (int2*)p;                    p += (size_t)TOT * 8;
    float* s0   = (float*)p;                   p += (size_t)N_ * 4;
    float* d0   = (float*)p;                   p += (size_t)N_ * 4;
    float* bns0 = (float*)p;                   p += 256 * 4;
    float* bns1 = (float*)p;                   p += 128 * 4;
    int* gcnt   = (int*)p;                     p += 512 * 4;
    int* gbase  = (int*)p;                     p += 514 * 4;
    int* gnext  = (int*)p;                     p += 512 * 4;
    int* rowp   = (int*)p;                     p += (size_t)(N_ + 2) * 4;
    int* csr    = (int*)p;                     p += (size_t)TOT * 4;
    unsigned short* Wp0 = (unsigned short*)p;  p += 128 * 128 * 2;
    unsigned short* Wp1 = (unsigned short*)p;  p += 128 * 64 * 2;

    hipMemsetAsync(gcnt, 0, 512 * 4, stream);
    hipMemsetAsync(bns0, 0, 384 * 4, stream);   // bns0 + bns1

    // CSR build (bucketed)
    const int ebBlocks = (TOT + 8191) / 8192;
    k_hist<<<ebBlocks, 512, 0, stream>>>(ei, E_, N_, nbk, gcnt);
    k_bscan<<<1, 512, 0, stream>>>(gcnt, gbase, gnext, nbk);
    k_bucket<<<ebBlocks, 512, 0, stream>>>(ei, E_, N_, nbk, gnext, bbuf);
    k_csr2<<<nbk, 256, 0, stream>>>(bbuf, gbase, rowp, csr, N_, nbk);

    // W packing
    k_packw<128><<<64, 256, 0, stream>>>(W0, Wp0);
    k_packw<64><<<32, 256, 0, stream>>>(W1, Wp1);

    const int gemmBlocks = (N_ + 63) / 64;
    const int waveBlocks = (N_ + 3) / 4;

    // ---- layer 0 ----
    k_gemm_mfma<128, false, false><<<gemmBlocks, 256, 0, stream>>>(
        x, Wp0, nullptr, nullptr, nullptr, as0, ad0, hb, s0, d0, N_);
    k_agg<128, true><<<waveBlocks, 256, 0, stream>>>(hb, s0, d0, rowp, csr, aggB, N_);
    k_bn_stats<128, true><<<256, 256, 0, stream>>>(aggB, bns0, N_);

    // ---- layer 1 (BN+ReLU fused into GEMM A-load, bf16 A) ----
    k_gemm_mfma<64, true, true><<<gemmBlocks, 256, 0, stream>>>(
        aggB, Wp1, bns0, g0, b0, as1, ad1, hb, s0, d0, N_);
    k_agg<64, false><<<waveBlocks, 256, 0, stream>>>(hb, s0, d0, rowp, csr, agg1, N_);
    k_bn_stats<64, false><<<256, 256, 0, stream>>>(agg1, bns1, N_);
    k_bn_apply<64><<<(int)(((size_t)N_ * 64 + 255) / 256), 256, 0, stream>>>(
        agg1, bns1, g1, b1, out, N_);
}